// Round 4
// baseline (291.249 us; speedup 1.0000x reference)
//
#include <hip/hip_runtime.h>

// ExponentialUnitNorm, 2-kernel split scan with LDS-staged full-width I/O.
// All global traffic is 16 B/lane linear float4 (chunk slabs are contiguous
// and 16B-aligned: (b*2000+c*40)*3848 B is a multiple of 16). The per-f
// sequential scan runs out of LDS (b64 reads, 2-way aliasing = free).
//   pass1: stage 8 rows -> scan accumulate -> per-chunk partials B[b,c,f]
//   pass2: entry state = W=24 window over partials (validated: absmax
//          0.03125 = 1 bf16 ulp), then stage/scan/normalize, writeback to
//          LDS in place, linear float4 NT store (keeps x L3-resident).
// No spin, no atomics, no memset. 800 blocks, 30.8 KB LDS -> ~3-5 blocks/CU.

#define ALPHA_F 0.99f
#define OMA_F   0.01f
#define EPS_F   1e-14f

typedef float f32x4 __attribute__((ext_vector_type(4)));  // native vec for NT store

constexpr int Bn = 16;
constexpr int Tn = 2000;
constexpr int Fn = 481;            // complex bins per row (float2)
constexpr int NC = 50;             // chunks along T
constexpr int L  = Tn / NC;        // 40 rows per chunk
constexpr int ST = 8;              // rows per LDS stage
constexpr int NS = L / ST;         // 5 stages per chunk
constexpr int F4S = ST * Fn / 2;   // 1924 float4 per stage (30784 B)
constexpr int TAIL = F4S - 7 * 256;  // 132
constexpr int W  = 24;             // lookback window, aL^24 = 6.4e-5
#define ALPHA_L 0.668971758f       // 0.99^40

__global__ __launch_bounds__(256) void eun_pass1(
    const float* __restrict__ x, float* __restrict__ part) {
  __shared__ float4 lds[F4S];
  const int tid = threadIdx.x;
  const int c = blockIdx.x, b = blockIdx.y;

  // chunk base in float4 units: (b*2000 + c*40) * 962 floats / 4
  const float4* xb = (const float4*)x + (size_t)(b * 500 + c * 10) * 962;

  const int f1 = tid;          // < 481 always
  const int f2 = tid + 256;    // valid iff tid < 225
  float s1 = 0.f, s2 = 0.f;

  for (int st = 0; st < NS; ++st) {
    const float4* sb = xb + st * F4S;
    float4 v[8];
#pragma unroll
    for (int j = 0; j < 7; ++j) v[j] = sb[tid + 256 * j];
    if (tid < TAIL) v[7] = sb[tid + 256 * 7];
#pragma unroll
    for (int j = 0; j < 7; ++j) lds[tid + 256 * j] = v[j];
    if (tid < TAIL) lds[tid + 256 * 7] = v[7];
    __syncthreads();

    const float2* l2 = (const float2*)lds;
#pragma unroll
    for (int t = 0; t < ST; ++t) {
      float2 a = l2[t * Fn + f1];
      float m = sqrtf(fmaxf(fmaf(a.x, a.x, a.y * a.y), EPS_F));
      s1 = fmaf(ALPHA_F, s1, OMA_F * m);
      if (f2 < Fn) {
        float2 q = l2[t * Fn + f2];
        float m2 = sqrtf(fmaxf(fmaf(q.x, q.x, q.y * q.y), EPS_F));
        s2 = fmaf(ALPHA_F, s2, OMA_F * m2);
      }
    }
    __syncthreads();
  }
  float* pp = part + ((size_t)b * NC + c) * Fn;
  pp[f1] = s1;
  if (f2 < Fn) pp[f2] = s2;
}

__global__ __launch_bounds__(256) void eun_pass2(
    const float* __restrict__ x, const float* __restrict__ part,
    const float* __restrict__ init_state, float* __restrict__ out) {
  __shared__ float4 lds[F4S];
  const int tid = threadIdx.x;
  const int c = blockIdx.x, b = blockIdx.y;

  const size_t cb = (size_t)(b * 500 + c * 10) * 962;
  const float4* xb = (const float4*)x + cb;
  f32x4*        ob = (f32x4*)out + cb;

  const int f1 = tid, f2 = tid + 256;

  // ---- chunk-entry state: W-window weighted sum of predecessor partials ----
  const float* pb = part + (size_t)b * NC * Fn;
  const int n = (c < W) ? c : W;  // uniform across block
  float pv1[W], pv2[W];
#pragma unroll
  for (int k = 0; k < W; ++k)
    if (k < n) {
      pv1[k] = pb[(size_t)(c - 1 - k) * Fn + f1];
      if (f2 < Fn) pv2[k] = pb[(size_t)(c - 1 - k) * Fn + f2];
    }
  float s1 = 0.f, s2 = 0.f, w = 1.f;
#pragma unroll
  for (int k = 0; k < W; ++k)
    if (k < n) {
      s1 = fmaf(w, pv1[k], s1);
      if (f2 < Fn) s2 = fmaf(w, pv2[k], s2);
      w *= ALPHA_L;
    }
  if (c <= W) {  // w == aL^c here; exact for these chunks
    s1 = fmaf(w, init_state[f1], s1);
    if (f2 < Fn) s2 = fmaf(w, init_state[f2], s2);
  }

  // ---- staged scan + normalize ----
  for (int st = 0; st < NS; ++st) {
    const float4* sb = xb + st * F4S;
    float4 v[8];
#pragma unroll
    for (int j = 0; j < 7; ++j) v[j] = sb[tid + 256 * j];
    if (tid < TAIL) v[7] = sb[tid + 256 * 7];
#pragma unroll
    for (int j = 0; j < 7; ++j) lds[tid + 256 * j] = v[j];
    if (tid < TAIL) lds[tid + 256 * 7] = v[7];
    __syncthreads();

    float2* l2 = (float2*)lds;
#pragma unroll
    for (int t = 0; t < ST; ++t) {
      float2 a = l2[t * Fn + f1];
      float m = sqrtf(fmaxf(fmaf(a.x, a.x, a.y * a.y), EPS_F));
      s1 = fmaf(ALPHA_F, s1, OMA_F * m);
      float inv1 = rsqrtf(s1);
      l2[t * Fn + f1] = make_float2(a.x * inv1, a.y * inv1);
      if (f2 < Fn) {
        float2 q = l2[t * Fn + f2];
        float m2 = sqrtf(fmaxf(fmaf(q.x, q.x, q.y * q.y), EPS_F));
        s2 = fmaf(ALPHA_F, s2, OMA_F * m2);
        float inv2 = rsqrtf(s2);
        l2[t * Fn + f2] = make_float2(q.x * inv2, q.y * inv2);
      }
    }
    __syncthreads();

    f32x4* obs = ob + st * F4S;
    const f32x4* ls = (const f32x4*)lds;
#pragma unroll
    for (int j = 0; j < 7; ++j) {
      f32x4 o = ls[tid + 256 * j];
      __builtin_nontemporal_store(o, obs + tid + 256 * j);  // out never re-read
    }
    if (tid < TAIL) {
      f32x4 o = ls[tid + 256 * 7];
      __builtin_nontemporal_store(o, obs + tid + 256 * 7);
    }
    __syncthreads();  // before next stage overwrites LDS
  }
}

extern "C" void kernel_launch(void* const* d_in, const int* in_sizes, int n_in,
                              void* d_out, int out_size, void* d_ws, size_t ws_size,
                              hipStream_t stream) {
  const float* x    = (const float*)d_in[0];
  const float* init = (const float*)d_in[1];
  float* out        = (float*)d_out;
  float* part       = (float*)d_ws;  // Bn*NC*Fn floats = 1.54 MB

  dim3 grid(NC, Bn);  // 50 x 16 = 800 blocks, one per (chunk, batch)
  eun_pass1<<<grid, dim3(256), 0, stream>>>(x, part);
  eun_pass2<<<grid, dim3(256), 0, stream>>>(x, part, init, out);
}

// Round 5
// 239.351 us; speedup vs baseline: 1.2168x; 1.2168x over previous
//
#include <hip/hip_runtime.h>

// ExponentialUnitNorm, 3-kernel split scan, max-MLP variant of the proven
// R0 structure (strided float2 access; wave reads 512 B contiguous/row):
//   pass1: per-chunk partials. NC=100 chunks (L=20 rows) -> 3200 blocks
//          (12.5/CU); ALL 20 row-loads issued before any wait (10 KB
//          in flight per wave). No barriers, no LDS, no spins.
//   mid:   in-place partials->chunk-entry-states (same 3.08 MB ws as R0).
//   pass2: rescan chunk from L3-resident x, normalize, NT-store out
//          (NT: out never re-read; keeps x resident for the stream).
// Known inherited cost: harness fill leaves ~117 MB dirty out-lines in
// cache; they write back during pass1 (seen R4: WRITE 117 MB). Unavoidable.
// Comparison is bf16-quantized; absmax floor 0.03125 = 1 bf16 ulp.

#define ALPHA_F 0.99f
#define OMA_F   0.01f
#define EPS_F   1e-14f

constexpr int Bn = 16;
constexpr int Tn = 2000;
constexpr int Fn = 481;
constexpr int NC = 100;         // chunks along T
constexpr int L  = Tn / NC;     // 20 rows per chunk
constexpr int MT = 25;          // mid-kernel tile (NC % MT == 0)
#define ALPHA_L 0.817906938f    // 0.99^20

__global__ __launch_bounds__(256) void eun_pass1(
    const float* __restrict__ x, float* __restrict__ part) {
  const int f = blockIdx.x * blockDim.x + threadIdx.x;
  if (f >= Fn) return;
  const int b = blockIdx.y;
  const int c = blockIdx.z;

  const size_t stride = (size_t)Fn * 2;
  const float* xp = x + ((size_t)b * Tn + (size_t)c * L) * stride + (size_t)f * 2;

  // all 20 loads issued back-to-back: 20 x 512 B per wave in flight
  float2 v[L];
#pragma unroll
  for (int j = 0; j < L; ++j)
    v[j] = *(const float2*)(xp + (size_t)j * stride);

  float s = 0.f;
#pragma unroll
  for (int j = 0; j < L; ++j) {
    float m = sqrtf(fmaxf(fmaf(v[j].x, v[j].x, v[j].y * v[j].y), EPS_F));
    s = fmaf(ALPHA_F, s, OMA_F * m);
  }
  part[((size_t)b * NC + c) * Fn + f] = s;
}

// In-place: part[b,c,f] (chunk partial B_c) -> chunk-entry state S_c.
// Each (b,f) column owned by one thread; tiles of 25 keep VGPRs sane.
__global__ __launch_bounds__(256) void eun_mid(
    const float* __restrict__ init_state, float* __restrict__ part) {
  const int f = blockIdx.x * blockDim.x + threadIdx.x;
  if (f >= Fn) return;
  const int b = blockIdx.y;

  float* pp = part + (size_t)b * NC * Fn + f;
  float s = init_state[f];
  for (int c0 = 0; c0 < NC; c0 += MT) {
    float p[MT];
#pragma unroll
    for (int k = 0; k < MT; ++k) p[k] = pp[(size_t)(c0 + k) * Fn];
#pragma unroll
    for (int k = 0; k < MT; ++k) {
      pp[(size_t)(c0 + k) * Fn] = s;          // S_c over B_c, in place
      s = fmaf(s, ALPHA_L, p[k]);             // S_{c+1} = aL*S_c + B_c
    }
  }
}

__global__ __launch_bounds__(256) void eun_pass2(
    const float* __restrict__ x, const float* __restrict__ start,
    float* __restrict__ out) {
  const int f = blockIdx.x * blockDim.x + threadIdx.x;
  if (f >= Fn) return;
  const int b = blockIdx.y;
  const int c = blockIdx.z;

  float s = start[((size_t)b * NC + c) * Fn + f];

  const size_t stride = (size_t)Fn * 2;
  const size_t off = ((size_t)b * Tn + (size_t)c * L) * stride + (size_t)f * 2;
  const float* xp = x + off;
  float*       op = out + off;

  float2 v[L];
#pragma unroll
  for (int j = 0; j < L; ++j)
    v[j] = *(const float2*)(xp + (size_t)j * stride);

#pragma unroll
  for (int j = 0; j < L; ++j) {
    float m = sqrtf(fmaxf(fmaf(v[j].x, v[j].x, v[j].y * v[j].y), EPS_F));
    s = fmaf(ALPHA_F, s, OMA_F * m);
    float inv = rsqrtf(s);
    union { float2 f2; unsigned long long u; } cvt;
    cvt.f2 = make_float2(v[j].x * inv, v[j].y * inv);
    // out is never re-read: bypass caches so x stays L3-resident.
    __builtin_nontemporal_store(cvt.u,
        (unsigned long long*)(op + (size_t)j * stride));
  }
}

extern "C" void kernel_launch(void* const* d_in, const int* in_sizes, int n_in,
                              void* d_out, int out_size, void* d_ws, size_t ws_size,
                              hipStream_t stream) {
  const float* x    = (const float*)d_in[0];
  const float* init = (const float*)d_in[1];
  float* out        = (float*)d_out;
  float* part       = (float*)d_ws;  // Bn*NC*Fn floats = 3.08 MB (as in R0)

  dim3 grid3((Fn + 255) / 256, Bn, NC);  // 2 x 16 x 100 = 3200 blocks
  eun_pass1<<<grid3, dim3(256), 0, stream>>>(x, part);
  eun_mid<<<dim3((Fn + 255) / 256, Bn), dim3(256), 0, stream>>>(init, part);
  eun_pass2<<<grid3, dim3(256), 0, stream>>>(x, part, out);
}

// Round 6
// 238.374 us; speedup vs baseline: 1.2218x; 1.0041x over previous
//
#include <hip/hip_runtime.h>
#include <hip/hip_cooperative_groups.h>

namespace cg = cooperative_groups;

// ExponentialUnitNorm, single cooperative kernel (grid.sync), 3 phases:
//   A: per-chunk partial B[b,c,f], x streamed from HBM (123 MB), 10-deep
//      load batches, strided float2 (proven R0/R5 form). No barriers.
//   sync: grid-wide barrier (device-scope fence) -> all partials visible.
//      Replaces R1's 49-deep spin chain AND the 2 kernel-boundary drains.
//   C: chunk-entry state via W=24 window over predecessor partials
//      (aL^24 = 6.4e-5; validated R2/R4, absmax 0.03125 = 1 bf16 ulp).
//      Batched independent loads, no spin - data is ready after sync.
//   D: rescan chunk (x now L3-resident), normalize, NT-store out
//      (out never re-read; NT keeps x resident for other blocks).
// Co-residency: 1600 blocks, __launch_bounds__(256,7) caps VGPR <= 73 ->
// 7 blocks/CU * 256 CU = 1792 >= 1600. Runtime occupancy check falls back
// to the proven R5 3-kernel path if capacity is insufficient.

#define ALPHA_F 0.99f
#define OMA_F   0.01f
#define EPS_F   1e-14f

constexpr int Bn = 16;
constexpr int Tn = 2000;
constexpr int Fn = 481;
constexpr int NC = 50;          // chunks along T (coop path)
constexpr int L  = Tn / NC;     // 40 rows per chunk
constexpr int UN = 10;          // load batch depth; L % UN == 0
constexpr int W  = 24;          // lookback window
#define ALPHA_L 0.668971758f    // 0.99^40

__global__ __launch_bounds__(256, 7) void eun_coop(
    const float* __restrict__ x, const float* __restrict__ init_state,
    float* __restrict__ out, float* __restrict__ part) {
  const int f = blockIdx.x * 256 + threadIdx.x;
  const int b = blockIdx.y;
  const int c = blockIdx.z;
  const bool act = (f < Fn);

  const size_t stride = (size_t)Fn * 2;
  const size_t off = ((size_t)b * Tn + (size_t)c * L) * stride + (size_t)f * 2;

  // ---- Phase A: local chunk partial (x from HBM) ----
  if (act) {
    const float* xp = x + off;
    float p = 0.f;
    for (int t0 = 0; t0 < L; t0 += UN) {
      float2 v[UN];
#pragma unroll
      for (int j = 0; j < UN; ++j)
        v[j] = *(const float2*)(xp + (size_t)j * stride);
#pragma unroll
      for (int j = 0; j < UN; ++j) {
        float m = sqrtf(fmaxf(fmaf(v[j].x, v[j].x, v[j].y * v[j].y), EPS_F));
        p = fmaf(ALPHA_F, p, OMA_F * m);
      }
      xp += (size_t)UN * stride;
    }
    part[((size_t)b * NC + c) * Fn + f] = p;
  }

  cg::this_grid().sync();   // all threads (incl. f>=Fn) participate

  if (!act) return;

  // ---- Phase C: entry state = W-window weighted sum of predecessors ----
  const float* pb = part + (size_t)b * NC * Fn + f;
  const int n = (c < W) ? c : W;  // uniform across block
  float s = 0.f, w = 1.f;
#pragma unroll
  for (int k = 0; k < W; ++k)
    if (k < n) {
      s = fmaf(w, pb[(size_t)(c - 1 - k) * Fn], s);
      w *= ALPHA_L;
    }
  if (c <= W) s = fmaf(w, init_state[f], s);  // w == aL^c here; exact

  // ---- Phase D: rescan (x L3-resident), normalize, NT-store ----
  const float* xp = x + off;
  float*       op = out + off;
  for (int t0 = 0; t0 < L; t0 += UN) {
    float2 v[UN];
#pragma unroll
    for (int j = 0; j < UN; ++j)
      v[j] = *(const float2*)(xp + (size_t)j * stride);
#pragma unroll
    for (int j = 0; j < UN; ++j) {
      float m = sqrtf(fmaxf(fmaf(v[j].x, v[j].x, v[j].y * v[j].y), EPS_F));
      s = fmaf(ALPHA_F, s, OMA_F * m);
      float inv = rsqrtf(s);
      union { float2 f2; unsigned long long u; } cvt;
      cvt.f2 = make_float2(v[j].x * inv, v[j].y * inv);
      __builtin_nontemporal_store(cvt.u,
          (unsigned long long*)(op + (size_t)j * stride));
    }
    xp += (size_t)UN * stride;
    op += (size_t)UN * stride;
  }
}

// ---------------- Fallback: proven R5 3-kernel path ----------------
constexpr int NCf = 100;        // chunks along T (fallback)
constexpr int Lf  = Tn / NCf;   // 20
constexpr int MT  = 25;
#define ALPHA_LF 0.817906938f   // 0.99^20

__global__ __launch_bounds__(256) void eun_pass1(
    const float* __restrict__ x, float* __restrict__ part) {
  const int f = blockIdx.x * blockDim.x + threadIdx.x;
  if (f >= Fn) return;
  const int b = blockIdx.y, c = blockIdx.z;
  const size_t stride = (size_t)Fn * 2;
  const float* xp = x + ((size_t)b * Tn + (size_t)c * Lf) * stride + (size_t)f * 2;
  float2 v[Lf];
#pragma unroll
  for (int j = 0; j < Lf; ++j) v[j] = *(const float2*)(xp + (size_t)j * stride);
  float s = 0.f;
#pragma unroll
  for (int j = 0; j < Lf; ++j) {
    float m = sqrtf(fmaxf(fmaf(v[j].x, v[j].x, v[j].y * v[j].y), EPS_F));
    s = fmaf(ALPHA_F, s, OMA_F * m);
  }
  part[((size_t)b * NCf + c) * Fn + f] = s;
}

__global__ __launch_bounds__(256) void eun_mid(
    const float* __restrict__ init_state, float* __restrict__ part) {
  const int f = blockIdx.x * blockDim.x + threadIdx.x;
  if (f >= Fn) return;
  const int b = blockIdx.y;
  float* pp = part + (size_t)b * NCf * Fn + f;
  float s = init_state[f];
  for (int c0 = 0; c0 < NCf; c0 += MT) {
    float p[MT];
#pragma unroll
    for (int k = 0; k < MT; ++k) p[k] = pp[(size_t)(c0 + k) * Fn];
#pragma unroll
    for (int k = 0; k < MT; ++k) {
      pp[(size_t)(c0 + k) * Fn] = s;
      s = fmaf(s, ALPHA_LF, p[k]);
    }
  }
}

__global__ __launch_bounds__(256) void eun_pass2(
    const float* __restrict__ x, const float* __restrict__ start,
    float* __restrict__ out) {
  const int f = blockIdx.x * blockDim.x + threadIdx.x;
  if (f >= Fn) return;
  const int b = blockIdx.y, c = blockIdx.z;
  float s = start[((size_t)b * NCf + c) * Fn + f];
  const size_t stride = (size_t)Fn * 2;
  const size_t off = ((size_t)b * Tn + (size_t)c * Lf) * stride + (size_t)f * 2;
  const float* xp = x + off;
  float*       op = out + off;
  float2 v[Lf];
#pragma unroll
  for (int j = 0; j < Lf; ++j) v[j] = *(const float2*)(xp + (size_t)j * stride);
#pragma unroll
  for (int j = 0; j < Lf; ++j) {
    float m = sqrtf(fmaxf(fmaf(v[j].x, v[j].x, v[j].y * v[j].y), EPS_F));
    s = fmaf(ALPHA_F, s, OMA_F * m);
    float inv = rsqrtf(s);
    union { float2 f2; unsigned long long u; } cvt;
    cvt.f2 = make_float2(v[j].x * inv, v[j].y * inv);
    __builtin_nontemporal_store(cvt.u,
        (unsigned long long*)(op + (size_t)j * stride));
  }
}

extern "C" void kernel_launch(void* const* d_in, const int* in_sizes, int n_in,
                              void* d_out, int out_size, void* d_ws, size_t ws_size,
                              hipStream_t stream) {
  const float* x    = (const float*)d_in[0];
  const float* init = (const float*)d_in[1];
  float* out        = (float*)d_out;
  float* part       = (float*)d_ws;  // coop: 1.54 MB; fallback: 3.08 MB

  // Capacity check (pure host computation; capture-safe).
  int maxB = 0;
  (void)hipOccupancyMaxActiveBlocksPerMultiprocessor(&maxB, (const void*)eun_coop,
                                                     256, 0);
  const int needed = 2 * Bn * NC;             // 1600 blocks
  if (maxB * 256 >= needed) {                 // 256 CUs on MI355X
    void* args[] = {(void*)&x, (void*)&init, (void*)&out, (void*)&part};
    (void)hipLaunchCooperativeKernel((const void*)eun_coop,
                                     dim3(2, Bn, NC), dim3(256),
                                     args, 0, stream);
  } else {
    dim3 grid3((Fn + 255) / 256, Bn, NCf);
    eun_pass1<<<grid3, dim3(256), 0, stream>>>(x, part);
    eun_mid<<<dim3((Fn + 255) / 256, Bn), dim3(256), 0, stream>>>(init, part);
    eun_pass2<<<grid3, dim3(256), 0, stream>>>(x, part, out);
  }
}